// Round 1
// baseline (2502.525 us; speedup 1.0000x reference)
//
#include <hip/hip_runtime.h>
#include <hip/hip_bf16.h>
#include <cstdint>

// Problem dims (fixed by reference)
#define NROWS 8192
#define KDIM  4096
#define ODIM  16384

typedef __attribute__((ext_vector_type(8))) short  short8;
typedef __attribute__((ext_vector_type(4))) float  f32x4;

constexpr int BM = 128, BN = 128, BK = 32;

// fp32 -> bf16 round-to-nearest-even
__device__ __forceinline__ ushort f2bf(float f) {
    uint32_t u = __float_as_uint(f);
    return (ushort)((u + 0x7fffu + ((u >> 16) & 1u)) >> 16);
}

__device__ __forceinline__ void gload_lds16(const void* g, void* l) {
    __builtin_amdgcn_global_load_lds(
        (const __attribute__((address_space(1))) void*)g,
        (__attribute__((address_space(3))) void*)l, 16, 0, 0);
}

// ---------------- prep kernels (fast path) ----------------

// x fp32 -> bf16, 8 elems/thread
__global__ __launch_bounds__(256) void prep_x_k(const float* __restrict__ x,
                                                ushort* __restrict__ xb) {
    size_t i = ((size_t)blockIdx.x * 256 + threadIdx.x) * 8;
    f32x4 a = *(const f32x4*)(x + i);
    f32x4 b = *(const f32x4*)(x + i + 4);
    short8 p;
    p[0] = (short)f2bf(a[0]); p[1] = (short)f2bf(a[1]);
    p[2] = (short)f2bf(a[2]); p[3] = (short)f2bf(a[3]);
    p[4] = (short)f2bf(b[0]); p[5] = (short)f2bf(b[1]);
    p[6] = (short)f2bf(b[2]); p[7] = (short)f2bf(b[3]);
    *(short8*)(xb + i) = p;
}

// W = mu + exp(ls)*eps -> bf16, 8 elems/thread
__global__ __launch_bounds__(256) void prep_w_k(const float* __restrict__ mu,
                                                const float* __restrict__ ls,
                                                const float* __restrict__ ep,
                                                ushort* __restrict__ wb) {
    size_t i = ((size_t)blockIdx.x * 256 + threadIdx.x) * 8;
    f32x4 m0 = *(const f32x4*)(mu + i), m1 = *(const f32x4*)(mu + i + 4);
    f32x4 s0 = *(const f32x4*)(ls + i), s1 = *(const f32x4*)(ls + i + 4);
    f32x4 e0 = *(const f32x4*)(ep + i), e1 = *(const f32x4*)(ep + i + 4);
    short8 p;
    p[0] = (short)f2bf(m0[0] + __expf(s0[0]) * e0[0]);
    p[1] = (short)f2bf(m0[1] + __expf(s0[1]) * e0[1]);
    p[2] = (short)f2bf(m0[2] + __expf(s0[2]) * e0[2]);
    p[3] = (short)f2bf(m0[3] + __expf(s0[3]) * e0[3]);
    p[4] = (short)f2bf(m1[0] + __expf(s1[0]) * e1[0]);
    p[5] = (short)f2bf(m1[1] + __expf(s1[1]) * e1[1]);
    p[6] = (short)f2bf(m1[2] + __expf(s1[2]) * e1[2]);
    p[7] = (short)f2bf(m1[3] + __expf(s1[3]) * e1[3]);
    *(short8*)(wb + i) = p;
}

__global__ __launch_bounds__(256) void prep_b_k(const float* __restrict__ bmu,
                                                const float* __restrict__ bls,
                                                const float* __restrict__ eb,
                                                float* __restrict__ bws) {
    int i = blockIdx.x * 256 + threadIdx.x;
    bws[i] = bmu[i] + __expf(bls[i]) * eb[i];
}

// ---------------- GEMM: C[n][o] = sum_k X[n][k]*W[o][k] + bias[o] ----------------
// m97-style 128x128 tile, BK=32, 4 waves (2x2), 16x16x32 bf16 MFMA.
// FUSED=false: reads precomputed bf16 from ws via global_load_lds (fast).
// FUSED=true : reg-stages with on-the-fly convert/sample (ws-too-small fallback).

template <bool FUSED>
__global__ __launch_bounds__(256, 2) void gemm_k(
    const ushort* __restrict__ Xb, const ushort* __restrict__ Wb,
    const float* __restrict__ Bws,
    const float* __restrict__ Xf, const float* __restrict__ Wmu,
    const float* __restrict__ Wls, const float* __restrict__ Ew,
    const float* __restrict__ Bmu, const float* __restrict__ Bls,
    const float* __restrict__ Eb, float* __restrict__ C) {
    __shared__ ushort ldsA[BM * BK];  // [row 0..127][k 0..31], 8 KiB
    __shared__ ushort ldsB[BN * BK];  // [ocol 0..127][k 0..31], 8 KiB

    const int tid  = threadIdx.x;
    const int w    = tid >> 6;     // wave 0..3
    const int lane = tid & 63;
    const int wm   = w >> 1, wn = w & 1;   // 2x2 wave grid, 64x64 per wave
    const int fr   = lane & 15;    // fragment row/col
    const int fk   = lane >> 4;    // k-group 0..3

    // XCD-aware bijective swizzle (nwg = 8192 divisible by 8)
    const int nwg  = gridDim.x;
    const int cpx  = nwg >> 3;
    const int orig = blockIdx.x;
    const int wg   = (orig & 7) * cpx + (orig >> 3);
    const int tm   = wg & 63;   // NROWS/BM = 64 ; consecutive wg share B-panel
    const int tn   = wg >> 6;   // ODIM/BN = 128

    f32x4 acc[4][4];
#pragma unroll
    for (int m = 0; m < 4; ++m)
#pragma unroll
        for (int n = 0; n < 4; ++n) acc[m][n] = (f32x4){0.f, 0.f, 0.f, 0.f};

    for (int t = 0; t < KDIM / BK; ++t) {
        const int k0 = t * BK;
        if constexpr (!FUSED) {
            // 8 chunks of 16 rows x 32 k for each of A,B; wave w stages chunks 2w,2w+1.
            // Lane layout: row = chunk*16 + lane/4, kbyte = (lane&3)*16 -> linear LDS.
#pragma unroll
            for (int ci = 0; ci < 2; ++ci) {
                const int c  = 2 * w + ci;
                const int gr = c * 16 + (lane >> 2);
                const int gk = k0 + (lane & 3) * 8;
                gload_lds16(Xb + (size_t)(tm * BM + gr) * KDIM + gk, &ldsA[c * 512]);
                gload_lds16(Wb + (size_t)(tn * BN + gr) * KDIM + gk, &ldsB[c * 512]);
            }
        } else {
            // reg-staged: 8 elems/thread, 2 sweeps cover 128x32
#pragma unroll
            for (int it = 0; it < 2; ++it) {
                const int e  = (it * 256 + tid) * 8;
                const int r  = e >> 5;
                const int kk = e & 31;
                {
                    const float* s = Xf + (size_t)(tm * BM + r) * KDIM + k0 + kk;
                    f32x4 a = *(const f32x4*)s, b = *(const f32x4*)(s + 4);
                    short8 p;
                    p[0] = (short)f2bf(a[0]); p[1] = (short)f2bf(a[1]);
                    p[2] = (short)f2bf(a[2]); p[3] = (short)f2bf(a[3]);
                    p[4] = (short)f2bf(b[0]); p[5] = (short)f2bf(b[1]);
                    p[6] = (short)f2bf(b[2]); p[7] = (short)f2bf(b[3]);
                    *(short8*)&ldsA[e] = p;
                }
                {
                    const size_t off = (size_t)(tn * BN + r) * KDIM + k0 + kk;
                    f32x4 m0 = *(const f32x4*)(Wmu + off), m1 = *(const f32x4*)(Wmu + off + 4);
                    f32x4 s0 = *(const f32x4*)(Wls + off), s1 = *(const f32x4*)(Wls + off + 4);
                    f32x4 e0 = *(const f32x4*)(Ew + off),  e1 = *(const f32x4*)(Ew + off + 4);
                    short8 p;
                    p[0] = (short)f2bf(m0[0] + __expf(s0[0]) * e0[0]);
                    p[1] = (short)f2bf(m0[1] + __expf(s0[1]) * e0[1]);
                    p[2] = (short)f2bf(m0[2] + __expf(s0[2]) * e0[2]);
                    p[3] = (short)f2bf(m0[3] + __expf(s0[3]) * e0[3]);
                    p[4] = (short)f2bf(m1[0] + __expf(s1[0]) * e1[0]);
                    p[5] = (short)f2bf(m1[1] + __expf(s1[1]) * e1[1]);
                    p[6] = (short)f2bf(m1[2] + __expf(s1[2]) * e1[2]);
                    p[7] = (short)f2bf(m1[3] + __expf(s1[3]) * e1[3]);
                    *(short8*)&ldsB[e] = p;
                }
            }
        }
        __syncthreads();  // drains vmcnt for global_load_lds / lds writes

        short8 af[4], bfv[4];
#pragma unroll
        for (int m = 0; m < 4; ++m)
            af[m] = *(const short8*)&ldsA[(wm * 64 + m * 16 + fr) * BK + fk * 8];
#pragma unroll
        for (int n = 0; n < 4; ++n)
            bfv[n] = *(const short8*)&ldsB[(wn * 64 + n * 16 + fr) * BK + fk * 8];
#pragma unroll
        for (int m = 0; m < 4; ++m)
#pragma unroll
            for (int n = 0; n < 4; ++n)
                acc[m][n] = __builtin_amdgcn_mfma_f32_16x16x32_bf16(af[m], bfv[n],
                                                                    acc[m][n], 0, 0, 0);
        __syncthreads();
    }

    // epilogue: C/D layout col = lane&15, row = (lane>>4)*4 + j  (m89-verified)
    const int ob = tn * BN + wn * 64;
    const int rb = tm * BM + wm * 64;
#pragma unroll
    for (int n = 0; n < 4; ++n) {
        const int col = ob + n * 16 + fr;
        float bv;
        if constexpr (FUSED)
            bv = Bmu[col] + __expf(Bls[col]) * Eb[col];
        else
            bv = Bws[col];
#pragma unroll
        for (int m = 0; m < 4; ++m) {
            const int r0 = rb + m * 16 + fk * 4;
#pragma unroll
            for (int j = 0; j < 4; ++j)
                C[(size_t)(r0 + j) * ODIM + col] = acc[m][n][j] + bv;
        }
    }
}

// ---------------- launch ----------------

extern "C" void kernel_launch(void* const* d_in, const int* in_sizes, int n_in,
                              void* d_out, int out_size, void* d_ws, size_t ws_size,
                              hipStream_t stream) {
    const float* x   = (const float*)d_in[0];
    const float* wmu = (const float*)d_in[1];
    const float* wls = (const float*)d_in[2];
    const float* bmu = (const float*)d_in[3];
    const float* bls = (const float*)d_in[4];
    const float* ew  = (const float*)d_in[5];
    const float* eb  = (const float*)d_in[6];
    float* out = (float*)d_out;

    const size_t xb_bytes = (size_t)NROWS * KDIM * sizeof(ushort);   // 64 MiB
    const size_t wb_bytes = (size_t)ODIM * KDIM * sizeof(ushort);    // 128 MiB
    const size_t bb_bytes = (size_t)ODIM * sizeof(float);            // 64 KiB
    const int nwg = (NROWS / BM) * (ODIM / BN);                      // 8192

    if (ws_size >= xb_bytes + wb_bytes + bb_bytes) {
        ushort* xb  = (ushort*)d_ws;
        ushort* wb  = (ushort*)((char*)d_ws + xb_bytes);
        float*  bws = (float*)((char*)d_ws + xb_bytes + wb_bytes);

        prep_x_k<<<(int)((size_t)NROWS * KDIM / (256 * 8)), 256, 0, stream>>>(x, xb);
        prep_w_k<<<(int)((size_t)ODIM * KDIM / (256 * 8)), 256, 0, stream>>>(wmu, wls, ew, wb);
        prep_b_k<<<ODIM / 256, 256, 0, stream>>>(bmu, bls, eb, bws);
        gemm_k<false><<<nwg, 256, 0, stream>>>(xb, wb, bws, nullptr, nullptr, nullptr,
                                               nullptr, nullptr, nullptr, nullptr, out);
    } else {
        gemm_k<true><<<nwg, 256, 0, stream>>>(nullptr, nullptr, nullptr, x, wmu, wls,
                                              ew, bmu, bls, eb, out);
    }
}